// Round 24
// baseline (177.620 us; speedup 1.0000x reference)
//
#include <hip/hip_runtime.h>
#include <hip/hip_fp16.h>

// B=8192, T=512, IN=1, H=20, OUT=1
#define B_TOTAL 8192
#define T_LEN   512
#define H       20
#define KSTEP   4
#define NSUPER  (T_LEN / KSTEP)     // 128
#define NEPOCH  (NSUPER / 2)        // 64 (2 superticks per barrier epoch)
#define CHUNK   128                 // x timesteps staged at once
#define XSTRC   132                 // chunk row stride: <=2-way bank alias (free)

typedef _Float16 f16x4 __attribute__((ext_vector_type(4)));
typedef float    f32x4 __attribute__((ext_vector_type(4)));
typedef unsigned int u32;

#if defined(__HIP_DEVICE_COMPILE__)
  #if __has_builtin(__builtin_amdgcn_mfma_f32_16x16x16_f16)
    #define MFMA16(a, b, c) __builtin_amdgcn_mfma_f32_16x16x16_f16((a), (b), (c), 0, 0, 0)
  #elif __has_builtin(__builtin_amdgcn_mfma_f32_16x16x16f16)
    #define MFMA16(a, b, c) __builtin_amdgcn_mfma_f32_16x16x16f16((a), (b), (c), 0, 0, 0)
  #else
    #error "no 16x16x16 f16 MFMA builtin on device"
  #endif
  #define SETPRIO(x) __builtin_amdgcn_s_setprio(x)
#else
  #define MFMA16(a, b, c) (c)   // host parse stub
  #define SETPRIO(x)
#endif

__device__ __forceinline__ float fast_tanh(float x) {
    float e = __builtin_amdgcn_exp2f(x * 2.885390081777927f);
    return fmaf(-2.0f, __builtin_amdgcn_rcpf(e + 1.0f), 1.0f);
}
__device__ __forceinline__ u32 pk2(float a, float b) {
    return __builtin_bit_cast(u32, __builtin_amdgcn_cvt_pkrtz(a, b));
}
__device__ __forceinline__ f16x4 u2f(uint2 v) { return __builtin_bit_cast(f16x4, v); }

// ---- prologue: pack 5 HxH matrices into 16x16x16 A-fragments (R18 verbatim) ----
__global__ void prep_w(const float* __restrict__ w_hh0, const float* __restrict__ w_ih1,
                       const float* __restrict__ w_hh1, const float* __restrict__ w_ih2,
                       const float* __restrict__ w_hh2, u32* __restrict__ ws)
{
    for (int e = threadIdx.x; e < 5 * 4 * 64; e += 256) {
        int l = e & 63, f = (e >> 6) & 3, m = e >> 8;
        const float* src = (m == 0) ? w_hh0 : (m == 1) ? w_ih1 :
                           (m == 2) ? w_hh1 : (m == 3) ? w_ih2 : w_hh2;
        int p = l & 15, g = l >> 4;
        int row = (f & 2) ? 16 + p : p;
        int kb  = ((f & 1) ? 16 : 0) + 4 * g;
        u32 d0 = 0, d1 = 0;
        if (row < H) {
            unsigned short h[4];
            #pragma unroll
            for (int i = 0; i < 4; ++i) {
                int k = kb + i;
                _Float16 v = (k < H) ? (_Float16)src[row * H + k] : (_Float16)0.f;
                h[i] = __builtin_bit_cast(unsigned short, v);
            }
            d0 = (u32)h[0] | ((u32)h[1] << 16);
            d1 = (u32)h[2] | ((u32)h[3] << 16);
        }
        ws[e * 2 + 0] = d0;
        ws[e * 2 + 1] = d1;
    }
}

#define TANHPK4(lo, hi, pkd, D1, D2) { \
    u32 a0 = pk2(fast_tanh((D1)[0]), fast_tanh((D1)[1])); \
    u32 a1 = pk2(fast_tanh((D1)[2]), fast_tanh((D1)[3])); \
    u32 a2 = pk2(fast_tanh((D2)[0]), fast_tanh((D2)[1])); \
    u32 a3 = pk2(fast_tanh((D2)[2]), fast_tanh((D2)[3])); \
    lo = u2f(make_uint2(a0, a1)); \
    hi = u2f(make_uint2(a2, a3)); \
    pkd = make_uint4(a0, a1, a2, a3); \
}

// D-phase with SPLIT accumulators: two independent MFMAs + vector add
// (critical path = 1 MFMA instead of 2 chained).
#define W0SUP(m, dst) { \
    f32x4 P1[KSTEP], P2[KSTEP]; \
    _Pragma("unroll") \
    for (int s = 0; s < KSTEP; ++s) { \
        float xv = xs[b][(KSTEP * (m) + s) & (CHUNK - 1)]; \
        _Pragma("unroll") \
        for (int r = 0; r < 4; ++r) { \
            P1[s][r] = fmaf(xv, w0lo[r], bd1[r]); \
            P2[s][r] = fmaf(xv, w0hi[r], bd2[r]); \
        } \
    } \
    _Pragma("unroll") \
    for (int s = 0; s < KSTEP; ++s) { \
        f32x4 R1 = MFMA16(RAhi1, Hhi, Zf); \
        f32x4 R2 = MFMA16(RAhi2, Hhi, Zf); \
        f32x4 D1 = MFMA16(RAlo1, Hlo, P1[s]); D1 = D1 + R1; \
        f32x4 D2 = MFMA16(RAlo2, Hlo, P2[s]); D2 = D2 + R2; \
        uint4 pk; \
        TANHPK4(Hlo, Hhi, pk, D1, D2) \
        (dst)[(s << 6) + l] = pk; \
    } \
}

#define W1SUP(m, srcb, dst) { \
    f32x4 P1[KSTEP], P2[KSTEP]; \
    _Pragma("unroll") \
    for (int s = 0; s < KSTEP; ++s) { \
        uint4 v = (srcb)[(s << 6) + l]; \
        f16x4 Blo = u2f(make_uint2(v.x, v.y)); \
        f16x4 Bhi = u2f(make_uint2(v.z, v.w)); \
        P1[s] = MFMA16(IAlo1, Blo, bd1); P1[s] = MFMA16(IAhi1, Bhi, P1[s]); \
        P2[s] = MFMA16(IAlo2, Blo, bd2); P2[s] = MFMA16(IAhi2, Bhi, P2[s]); \
    } \
    _Pragma("unroll") \
    for (int s = 0; s < KSTEP; ++s) { \
        f32x4 R1 = MFMA16(RAhi1, Hhi, Zf); \
        f32x4 R2 = MFMA16(RAhi2, Hhi, Zf); \
        f32x4 D1 = MFMA16(RAlo1, Hlo, P1[s]); D1 = D1 + R1; \
        f32x4 D2 = MFMA16(RAlo2, Hlo, P2[s]); D2 = D2 + R2; \
        uint4 pk; \
        TANHPK4(Hlo, Hhi, pk, D1, D2) \
        (dst)[(s << 6) + l] = pk; \
    } \
}

#define W2SUP(m, srcb) { \
    f32x4 P1[KSTEP], P2[KSTEP]; \
    _Pragma("unroll") \
    for (int s = 0; s < KSTEP; ++s) { \
        uint4 v = (srcb)[(s << 6) + l]; \
        f16x4 Blo = u2f(make_uint2(v.x, v.y)); \
        f16x4 Bhi = u2f(make_uint2(v.z, v.w)); \
        P1[s] = MFMA16(IAlo1, Blo, bd1); P1[s] = MFMA16(IAhi1, Bhi, P1[s]); \
        P2[s] = MFMA16(IAlo2, Blo, bd2); P2[s] = MFMA16(IAhi2, Bhi, P2[s]); \
    } \
    _Pragma("unroll") \
    for (int s = 0; s < KSTEP; ++s) { \
        f32x4 R1 = MFMA16(RAhi1, Hhi, Zf); \
        f32x4 R2 = MFMA16(RAhi2, Hhi, Zf); \
        f32x4 D1 = MFMA16(RAlo1, Hlo, P1[s]); D1 = D1 + R1; \
        f32x4 D2 = MFMA16(RAlo2, Hlo, P2[s]); D2 = D2 + R2; \
        uint4 pk; \
        TANHPK4(Hlo, Hhi, pk, D1, D2) \
    } \
}

// 3 waves/block (one layer each), 16 batches, KSTEP=4, G=2 superticks per
// barrier epoch (4-deep parity handoff buffers -> 67 barriers instead of 130).
__global__ __launch_bounds__(192, 2) void rnn_mfma(
    const float* __restrict__ x,
    const float* __restrict__ w_ih0,
    const float* __restrict__ b_ih0, const float* __restrict__ b_hh0,
    const float* __restrict__ b_ih1, const float* __restrict__ b_hh1,
    const float* __restrict__ b_ih2, const float* __restrict__ b_hh2,
    const float* __restrict__ fc_w,  const float* __restrict__ fc_b,
    const u32* __restrict__ wpk,
    float* __restrict__ out)
{
    __shared__ __align__(16) float xs[16][XSTRC];           // 8.4 KB
    __shared__ __align__(16) uint4 h0b[2][2][KSTEP * 64];   // 16 KB [parity][sg]
    __shared__ __align__(16) uint4 h1b[2][2][KSTEP * 64];   // 16 KB

    const int tid = threadIdx.x;
    const int wv  = tid >> 6;
    const int l   = tid & 63;
    const int b   = l & 15;
    const int g   = l >> 4;
    const int gb0 = blockIdx.x * 16;

    // ---- stage x chunk 0 (cooperative) ----
    for (int i = tid; i < 16 * (CHUNK / 4); i += 192) {
        int row = i >> 5, col4 = i & 31;
        *(float4*)&xs[row][col4 * 4] =
            *(const float4*)(x + (size_t)(gb0 + row) * T_LEN + col4 * 4);
    }

    // ---- per-wave weight A-fragments ----
    const int mA = (wv == 1) ? 1 : 3;
    const int mB = (wv == 0) ? 0 : (wv == 1) ? 2 : 4;
    f16x4 IAlo1 = {}, IAhi1 = {}, IAlo2 = {}, IAhi2 = {};
    if (wv != 0) {
        IAlo1 = u2f(*(const uint2*)(wpk + ((mA * 4 + 0) * 64 + l) * 2));
        IAhi1 = u2f(*(const uint2*)(wpk + ((mA * 4 + 1) * 64 + l) * 2));
        IAlo2 = u2f(*(const uint2*)(wpk + ((mA * 4 + 2) * 64 + l) * 2));
        IAhi2 = u2f(*(const uint2*)(wpk + ((mA * 4 + 3) * 64 + l) * 2));
    }
    const f16x4 RAlo1 = u2f(*(const uint2*)(wpk + ((mB * 4 + 0) * 64 + l) * 2));
    const f16x4 RAhi1 = u2f(*(const uint2*)(wpk + ((mB * 4 + 1) * 64 + l) * 2));
    const f16x4 RAlo2 = u2f(*(const uint2*)(wpk + ((mB * 4 + 2) * 64 + l) * 2));
    const f16x4 RAhi2 = u2f(*(const uint2*)(wpk + ((mB * 4 + 3) * 64 + l) * 2));

    // ---- biases in D layout ----
    const float* bi = (wv == 0) ? b_ih0 : (wv == 1) ? b_ih1 : b_ih2;
    const float* bh = (wv == 0) ? b_hh0 : (wv == 1) ? b_hh1 : b_hh2;
    f32x4 bd1, bd2, w0lo, w0hi;
    #pragma unroll
    for (int r = 0; r < 4; ++r) {
        int j = 4 * g + r;
        bd1[r]  = bi[j] + bh[j];
        bd2[r]  = (g == 0) ? bi[16 + r] + bh[16 + r] : 0.f;
        w0lo[r] = w_ih0[j];
        w0hi[r] = (g == 0) ? w_ih0[16 + r] : 0.f;
    }
    const f32x4 Zf = {0.f, 0.f, 0.f, 0.f};

    // ---- recurrent state (own layer) ----
    f16x4 Hlo = {}, Hhi = {};

    // ---- epoch-pipelined diagonal schedule ----
    // Epoch M: wv0 -> superticks 2M,2M+1 (parity M&1); wv1 -> 2(M-1)+sg
    // (parity (M-1)&1); wv2 -> 2(M-2)+sg (reads h1b parity M&1).
    __syncthreads();                     // staging visible
    if (wv == 0) { W0SUP(0, &h0b[0][0][0]) W0SUP(1, &h0b[0][1][0]) }   // M=0
    __syncthreads();
    if (wv == 0) { W0SUP(2, &h0b[1][0][0]) W0SUP(3, &h0b[1][1][0]) }   // M=1
    else if (wv == 1) {
        W1SUP(0, &h0b[0][0][0], &h1b[0][0][0])
        W1SUP(1, &h0b[0][1][0], &h1b[0][1][0])
    }
    for (int M = 2; M < NEPOCH; ++M) {   // steady state
        __syncthreads();
        if (wv == 0) {
            if ((M & 15) == 0) {         // restage next 128-step x chunk
                const int tc = (M >> 4) * CHUNK;
                for (int i = l; i < 16 * (CHUNK / 4); i += 64) {
                    int row = i >> 5, col4 = i & 31;
                    *(float4*)&xs[row][col4 * 4] =
                        *(const float4*)(x + (size_t)(gb0 + row) * T_LEN + tc + col4 * 4);
                }
            }
            W0SUP(2 * M,     &h0b[M & 1][0][0])
            W0SUP(2 * M + 1, &h0b[M & 1][1][0])
        } else if (wv == 1) {
            SETPRIO(1);
            W1SUP(2 * (M - 1),     &h0b[(M - 1) & 1][0][0], &h1b[(M - 1) & 1][0][0])
            W1SUP(2 * (M - 1) + 1, &h0b[(M - 1) & 1][1][0], &h1b[(M - 1) & 1][1][0])
            SETPRIO(0);
        } else {
            SETPRIO(1);
            W2SUP(2 * (M - 2),     &h1b[M & 1][0][0])
            W2SUP(2 * (M - 2) + 1, &h1b[M & 1][1][0])
            SETPRIO(0);
        }
    }
    __syncthreads();                     // M = NEPOCH (64)
    if (wv == 1) {
        W1SUP(2 * (NEPOCH - 1),     &h0b[(NEPOCH - 1) & 1][0][0], &h1b[(NEPOCH - 1) & 1][0][0])
        W1SUP(2 * (NEPOCH - 1) + 1, &h0b[(NEPOCH - 1) & 1][1][0], &h1b[(NEPOCH - 1) & 1][1][0])
    } else if (wv == 2) {
        W2SUP(2 * (NEPOCH - 2),     &h1b[NEPOCH & 1][0][0])
        W2SUP(2 * (NEPOCH - 2) + 1, &h1b[NEPOCH & 1][1][0])
    }
    __syncthreads();                     // M = NEPOCH + 1 (65)
    if (wv == 2) {
        W2SUP(2 * (NEPOCH - 1),     &h1b[(NEPOCH + 1) & 1][0][0])
        W2SUP(2 * (NEPOCH - 1) + 1, &h1b[(NEPOCH + 1) & 1][1][0])
    }

    // ---- FC epilogue: wave2 holds h2(511) ----
    if (wv == 2) {
        float acc = 0.f;
        #pragma unroll
        for (int i = 0; i < 4; ++i)
            acc = fmaf((float)Hlo[i], fc_w[4 * g + i], acc);
        if (g == 0) {
            #pragma unroll
            for (int i = 0; i < 4; ++i)
                acc = fmaf((float)Hhi[i], fc_w[16 + i], acc);
        }
        acc += __shfl_xor(acc, 16);
        acc += __shfl_xor(acc, 32);
        if (l < 16) out[gb0 + l] = acc + fc_b[0];
    }
}

extern "C" void kernel_launch(void* const* d_in, const int* in_sizes, int n_in,
                              void* d_out, int out_size, void* d_ws, size_t ws_size,
                              hipStream_t stream) {
    const float* x     = (const float*)d_in[0];
    const float* w_ih0 = (const float*)d_in[1];
    const float* w_hh0 = (const float*)d_in[2];
    const float* b_ih0 = (const float*)d_in[3];
    const float* b_hh0 = (const float*)d_in[4];
    const float* w_ih1 = (const float*)d_in[5];
    const float* w_hh1 = (const float*)d_in[6];
    const float* b_ih1 = (const float*)d_in[7];
    const float* b_hh1 = (const float*)d_in[8];
    const float* w_ih2 = (const float*)d_in[9];
    const float* w_hh2 = (const float*)d_in[10];
    const float* b_ih2 = (const float*)d_in[11];
    const float* b_hh2 = (const float*)d_in[12];
    const float* fc_w  = (const float*)d_in[13];
    const float* fc_b  = (const float*)d_in[14];
    float* out = (float*)d_out;
    u32* wpk = (u32*)d_ws;   // 5 * 4 * 64 * 2 * 4 = 10240 B

    prep_w<<<1, 256, 0, stream>>>(w_hh0, w_ih1, w_hh1, w_ih2, w_hh2, wpk);

    rnn_mfma<<<B_TOTAL / 16, 192, 0, stream>>>(
        x, w_ih0, b_ih0, b_hh0, b_ih1, b_hh1, b_ih2, b_hh2,
        fc_w, fc_b, wpk, out);
}